// Round 1
// baseline (435.864 us; speedup 1.0000x reference)
//
#include <hip/hip_runtime.h>

typedef unsigned short u16;
typedef __attribute__((ext_vector_type(8))) short short8;
typedef __attribute__((ext_vector_type(4))) float float4v;

#define BTH (512*256*128)   // elements per output tensor
#define MASKV (-30000.0f)

__device__ __forceinline__ u16 f2bf(float f){
    union{float f; unsigned i;} v; v.f = f;
    unsigned x = v.i;
    unsigned r = (x + 0x7FFFu + ((x >> 16) & 1u)) >> 16;  // RNE
    return (u16)r;
}
__device__ __forceinline__ void store4bf(u16* dst, float4v v){
    dst[0] = f2bf(v[0]); dst[1] = f2bf(v[1]); dst[2] = f2bf(v[2]); dst[3] = f2bf(v[3]);
}

// ---------------- Kernel 0: f32 weights -> bf16 WT[3][128 n][128 k] in ws; fold C^-0.5 into Wq.
__global__ void wt_kernel(const float* __restrict__ Wq, const float* __restrict__ Wk,
                          const float* __restrict__ Wv, u16* __restrict__ WT){
    int idx = blockIdx.x * 256 + threadIdx.x;   // 0..49151
    int w   = idx >> 14;
    int rem = idx & 16383;
    int n = rem >> 7;
    int k = rem & 127;
    const float* src = (w == 0) ? Wq : (w == 1) ? Wk : Wv;
    float val = src[k * 128 + n];
    if (w == 0) val *= 0.08838834764831845f;    // 128^-0.5
    WT[idx] = f2bf(val);
}

// ============================================================================
// NEW PATH: proj_kernel emits f32 k,v outputs PLUS bf16 q/k/vT workspace copies;
// attn2_kernel streams all MFMA operands per-lane from global (no staging LDS,
// no barriers).  Needs ~96.1 MiB workspace; guarded by ws_size check below.
// ============================================================================

// proj: per 64-row block, q/k/v = x @ W.  q->bf16 ws, k->f32 out + bf16 ws,
// v->f32 out; vT (bf16 [b][h][t]) via swapped MFMA: D[h][t] = rows(WvT)·rows(x)^T.
__global__ __launch_bounds__(256) void proj_kernel(const float* __restrict__ x,
                                                   const u16* __restrict__ WT,
                                                   float* __restrict__ dout,
                                                   u16* __restrict__ qws,
                                                   u16* __restrict__ kws,
                                                   u16* __restrict__ vws){
    __shared__ u16 xs[64 * 136];    // x tile bf16, +8 pad -> conflict-free b128 frag reads
    int row0 = blockIdx.x * 64;
    int tid = threadIdx.x;
    int wave = tid >> 6, lane = tid & 63, lq = lane & 15, quad = lane >> 4;

    // stage x rows (f32 -> bf16), coalesced
    #pragma unroll
    for (int g = 0; g < 8; g++){
        int c2 = g*256 + tid;
        int r = c2 >> 5, f4 = c2 & 31;
        float4v xx = *(const float4v*)(x + (size_t)(row0 + r)*128 + f4*4);
        store4bf(xs + r*136 + f4*4, xx);
    }
    __syncthreads();

    // A-frags: full 64-row tile per wave (a[mt][ks])
    short8 a[4][4];
    #pragma unroll
    for (int mt = 0; mt < 4; mt++)
        #pragma unroll
        for (int ks = 0; ks < 4; ks++)
            a[mt][ks] = *(const short8*)(xs + (mt*16 + lq)*136 + ks*32 + quad*8);

    // ---- Q (w=0) and K (w=1): D[t][h] = rows(x)·rows(W^T)^T
    #pragma unroll
    for (int w = 0; w < 2; w++){
        #pragma unroll
        for (int nt2 = 0; nt2 < 2; nt2++){
            int gn = wave*32 + nt2*16;
            short8 bw[4];
            #pragma unroll
            for (int ks = 0; ks < 4; ks++)
                bw[ks] = *(const short8*)(WT + (size_t)w*16384 + (size_t)(gn + lq)*128 + ks*32 + quad*8);
            #pragma unroll
            for (int mt = 0; mt < 4; mt++){
                float4v c = {0.f, 0.f, 0.f, 0.f};
                #pragma unroll
                for (int ks = 0; ks < 4; ks++)
                    c = __builtin_amdgcn_mfma_f32_16x16x32_bf16(a[mt][ks], bw[ks], c, 0, 0, 0);
                int rowb = row0 + mt*16 + quad*4;
                if (w == 0){
                    #pragma unroll
                    for (int r = 0; r < 4; r++)
                        qws[(size_t)(rowb + r)*128 + gn + lq] = f2bf(c[r]);
                } else {
                    #pragma unroll
                    for (int r = 0; r < 4; r++){
                        dout[(size_t)BTH + (size_t)(rowb + r)*128 + gn + lq] = c[r];
                        kws[(size_t)(rowb + r)*128 + gn + lq] = f2bf(c[r]);
                    }
                }
            }
        }
    }

    // ---- V (f32 out only)
    #pragma unroll
    for (int nt2 = 0; nt2 < 2; nt2++){
        int gn = wave*32 + nt2*16;
        short8 bw[4];
        #pragma unroll
        for (int ks = 0; ks < 4; ks++)
            bw[ks] = *(const short8*)(WT + (size_t)2*16384 + (size_t)(gn + lq)*128 + ks*32 + quad*8);
        #pragma unroll
        for (int mt = 0; mt < 4; mt++){
            float4v c = {0.f, 0.f, 0.f, 0.f};
            #pragma unroll
            for (int ks = 0; ks < 4; ks++)
                c = __builtin_amdgcn_mfma_f32_16x16x32_bf16(a[mt][ks], bw[ks], c, 0, 0, 0);
            int rowb = row0 + mt*16 + quad*4;
            #pragma unroll
            for (int r = 0; r < 4; r++)
                dout[(size_t)2*BTH + (size_t)(rowb + r)*128 + gn + lq] = c[r];
        }
    }

    // ---- V^T bf16 image: swapped operands, A = Wv^T rows (WT layout), B = x rows (reuse a[][]).
    {
        int b = row0 >> 8, t0 = row0 & 255;
        #pragma unroll
        for (int mt2 = 0; mt2 < 2; mt2++){
            int gh = wave*32 + mt2*16;
            short8 av[4];
            #pragma unroll
            for (int ks = 0; ks < 4; ks++)
                av[ks] = *(const short8*)(WT + (size_t)2*16384 + (size_t)(gh + lq)*128 + ks*32 + quad*8);
            #pragma unroll
            for (int nt = 0; nt < 4; nt++){
                float4v c = {0.f, 0.f, 0.f, 0.f};
                #pragma unroll
                for (int ks = 0; ks < 4; ks++)
                    c = __builtin_amdgcn_mfma_f32_16x16x32_bf16(av[ks], a[nt][ks], c, 0, 0, 0);
                int hb = gh + quad*4;   // D row = h, D col = t(local)
                #pragma unroll
                for (int r = 0; r < 4; r++)
                    vws[((size_t)b*128 + hb + r)*256 + t0 + nt*16 + lq] = f2bf(c[r]);
            }
        }
    }
}

// attn2: barrier-free flash attention; all operands per-lane 16B global loads.
// LDS = per-wave P exchange only (same-wave RAW ordered by lgkmcnt).
__global__ __launch_bounds__(256) void attn2_kernel(const u16* __restrict__ qws,
                                                    const u16* __restrict__ kws,
                                                    const u16* __restrict__ vws,
                                                    float* __restrict__ dout){
    __shared__ u16 ps[4 * 16 * 72];  // per-wave P buffer [16 rows][64 keys]

    // XCD-chunked swizzle (2048 = 8*256): all 4 q-tiles of a batch -> same XCD's L2
    int lb = ((blockIdx.x & 7) << 8) | (blockIdx.x >> 3);
    int b = lb >> 2, qt = lb & 3;
    int tid = threadIdx.x;
    int wave = tid >> 6, lane = tid & 63, lq = lane & 15, quad = lane >> 4;
    int qrow = b*256 + qt*64 + wave*16;

    short8 qf[4];
    #pragma unroll
    for (int ks = 0; ks < 4; ks++)
        qf[ks] = *(const short8*)(qws + (size_t)(qrow + lq)*128 + ks*32 + quad*8);

    float4v oacc[8];
    #pragma unroll
    for (int i = 0; i < 8; i++) oacc[i] = (float4v){0.f, 0.f, 0.f, 0.f};
    float mrun[4] = {MASKV, MASKV, MASKV, MASKV};
    float lrun[4] = {0.f, 0.f, 0.f, 0.f};

    for (int kt = 0; kt <= qt; kt++){
        const u16* kp = kws + ((size_t)b*256 + kt*64)*128;          // K rows [key][h]
        const u16* vp = vws + (size_t)b*128*256 + kt*64;            // V^T rows [h][t]

        // S = Q K^T : wave's 16 rows x 64 keys
        float4v s4[4];
        #pragma unroll
        for (int nt = 0; nt < 4; nt++){
            float4v c = {0.f, 0.f, 0.f, 0.f};
            #pragma unroll
            for (int ks = 0; ks < 4; ks++){
                short8 bb = *(const short8*)(kp + (size_t)(nt*16 + lq)*128 + ks*32 + quad*8);
                c = __builtin_amdgcn_mfma_f32_16x16x32_bf16(qf[ks], bb, c, 0, 0, 0);
            }
            #pragma unroll
            for (int r = 0; r < 4; r++)
                c[r] = fminf(fmaxf(c[r], MASKV), 30000.0f);   // NaN/inf scrub insurance
            s4[nt] = c;
        }
        if (kt == qt){
            #pragma unroll
            for (int nt = 0; nt < 4; nt++)
                #pragma unroll
                for (int r = 0; r < 4; r++){
                    int ci = nt*16 + lq;
                    int ri = wave*16 + quad*4 + r;
                    if (ci > ri) s4[nt][r] = MASKV;
                }
        }
        // online softmax (quad's 16 lanes hold one row's 64 cols)
        float p[4][4];
        #pragma unroll
        for (int r = 0; r < 4; r++){
            float mx = fmaxf(fmaxf(s4[0][r], s4[1][r]), fmaxf(s4[2][r], s4[3][r]));
            mx = fmaxf(mx, __shfl_xor(mx, 1));
            mx = fmaxf(mx, __shfl_xor(mx, 2));
            mx = fmaxf(mx, __shfl_xor(mx, 4));
            mx = fmaxf(mx, __shfl_xor(mx, 8));
            float mnew = fmaxf(mrun[r], mx);
            float alpha = __expf(mrun[r] - mnew);
            float rs = 0.f;
            #pragma unroll
            for (int nt = 0; nt < 4; nt++){
                float pv = __expf(s4[nt][r] - mnew);
                p[nt][r] = pv;
                rs += pv;
            }
            rs += __shfl_xor(rs, 1);
            rs += __shfl_xor(rs, 2);
            rs += __shfl_xor(rs, 4);
            rs += __shfl_xor(rs, 8);
            lrun[r] = lrun[r] * alpha + rs;
            mrun[r] = mnew;
            #pragma unroll
            for (int o = 0; o < 8; o++) oacc[o][r] *= alpha;
        }
        // P: C/D-layout -> per-wave LDS -> A-layout (same-wave, no barrier needed)
        #pragma unroll
        for (int nt = 0; nt < 4; nt++)
            #pragma unroll
            for (int r = 0; r < 4; r++)
                ps[wave*1152 + (quad*4 + r)*72 + nt*16 + lq] = f2bf(p[nt][r]);
        // O += P V
        #pragma unroll
        for (int k2 = 0; k2 < 2; k2++){
            short8 pa = *(const short8*)(ps + wave*1152 + lq*72 + k2*32 + quad*8);
            #pragma unroll
            for (int o = 0; o < 8; o++){
                short8 bb = *(const short8*)(vp + (size_t)(o*16 + lq)*256 + k2*32 + quad*8);
                oacc[o] = __builtin_amdgcn_mfma_f32_16x16x32_bf16(pa, bb, oacc[o], 0, 0, 0);
            }
        }
    }
    // epilogue: out f32
    #pragma unroll
    for (int r = 0; r < 4; r++){
        float inv = 1.0f / lrun[r];
        int row = qrow + quad*4 + r;
        #pragma unroll
        for (int o = 0; o < 8; o++)
            dout[(size_t)row * 128 + o*16 + lq] = oacc[o][r] * inv;
    }
}

// ============================================================================
// FALLBACK PATH (previous verified kernels) — used if workspace is too small.
// ============================================================================

__global__ __launch_bounds__(256) void kv_kernel(const float* __restrict__ x,
                                                 const u16* __restrict__ WT,
                                                 float* __restrict__ dout){
    int row0 = blockIdx.x * 64;
    int tid = threadIdx.x;
    int wave = tid >> 6, lane = tid & 63, lq = lane & 15, quad = lane >> 4;

    short8 a[4][4];
    #pragma unroll
    for (int mt = 0; mt < 4; mt++)
        #pragma unroll
        for (int ks = 0; ks < 4; ks++){
            const float* px = x + (size_t)(row0 + mt*16 + lq)*128 + ks*32 + quad*8;
            float4v lo = *(const float4v*)px;
            float4v hi = *(const float4v*)(px + 4);
            short8 s;
            #pragma unroll
            for (int j = 0; j < 4; j++){
                s[j]     = (short)f2bf(lo[j]);
                s[j + 4] = (short)f2bf(hi[j]);
            }
            a[mt][ks] = s;
        }

    #pragma unroll
    for (int nt4 = 0; nt4 < 4; nt4++){
        int gn = wave*64 + nt4*16;
        short8 b[4];
        #pragma unroll
        for (int ks = 0; ks < 4; ks++)
            b[ks] = *(const short8*)(WT + (size_t)(128 + gn + lq)*128 + ks*32 + quad*8);
        float* outp = dout + (size_t)(1 + (gn >> 7)) * BTH;
        int h = (gn & 127) + lq;
        #pragma unroll
        for (int mt = 0; mt < 4; mt++){
            float4v c = {0.f, 0.f, 0.f, 0.f};
            #pragma unroll
            for (int ks = 0; ks < 4; ks++)
                c = __builtin_amdgcn_mfma_f32_16x16x32_bf16(a[mt][ks], b[ks], c, 0, 0, 0);
            int rowb = row0 + mt*16 + quad*4;
            #pragma unroll
            for (int r = 0; r < 4; r++)
                outp[(size_t)(rowb + r) * 128 + h] = c[r];
        }
    }
}

__global__ __launch_bounds__(256) void attn_kernel(const float* __restrict__ x,
                                                   const u16* __restrict__ WT,
                                                   float* __restrict__ dout){
    const float* kg = dout + (size_t)BTH;
    const float* vg = dout + (size_t)2 * BTH;

    __shared__ u16 ksm[64 * 136];
    __shared__ u16 qsm[64 * 136];
    __shared__ u16 vts[128 * 72];
    __shared__ u16 ps [4 * 16 * 72];

    int blk = blockIdx.x;
    int b = blk >> 2, qt = blk & 3;
    int tid = threadIdx.x;
    int wave = tid >> 6, lane = tid & 63, lq = lane & 15, quad = lane >> 4;
    int qrow0 = b * 256 + qt * 64;

    #pragma unroll
    for (int g = 0; g < 8; g++){
        int c2 = g*256 + tid;
        int r = c2 >> 5, f4 = c2 & 31;
        float4v xx = *(const float4v*)(x + (size_t)(qrow0 + r)*128 + f4*4);
        store4bf(ksm + r*136 + f4*4, xx);
    }
    __syncthreads();
    {
        short8 ax[4];
        #pragma unroll
        for (int ks = 0; ks < 4; ks++)
            ax[ks] = *(const short8*)(ksm + (wave*16 + lq)*136 + ks*32 + quad*8);
        #pragma unroll
        for (int nt8 = 0; nt8 < 8; nt8++){
            short8 bq[4];
            #pragma unroll
            for (int ks = 0; ks < 4; ks++)
                bq[ks] = *(const short8*)(WT + (size_t)(nt8*16 + lq)*128 + ks*32 + quad*8);
            float4v c = {0.f, 0.f, 0.f, 0.f};
            #pragma unroll
            for (int ks = 0; ks < 4; ks++)
                c = __builtin_amdgcn_mfma_f32_16x16x32_bf16(ax[ks], bq[ks], c, 0, 0, 0);
            #pragma unroll
            for (int r = 0; r < 4; r++)
                qsm[(wave*16 + quad*4 + r)*136 + nt8*16 + lq] = f2bf(c[r]);
        }
    }
    __syncthreads();
    short8 qf[4];
    #pragma unroll
    for (int ks = 0; ks < 4; ks++)
        qf[ks] = *(const short8*)(qsm + (wave*16 + lq)*136 + ks*32 + quad*8);

    float4v oacc[8];
    #pragma unroll
    for (int i = 0; i < 8; i++) oacc[i] = (float4v){0.f, 0.f, 0.f, 0.f};
    float mrun[4] = {MASKV, MASKV, MASKV, MASKV};
    float lrun[4] = {0.f, 0.f, 0.f, 0.f};

    for (int kt = 0; kt <= qt; kt++){
        int krow0 = b * 256 + kt * 64;
        __syncthreads();
        #pragma unroll
        for (int g = 0; g < 8; g++){
            int c2 = g*256 + tid;
            int r = c2 >> 5, f4 = c2 & 31;
            float4v kk = *(const float4v*)(kg + (size_t)(krow0 + r)*128 + f4*4);
            store4bf(ksm + r*136 + f4*4, kk);
        }
        #pragma unroll
        for (int g = 0; g < 8; g++){
            int c2 = g*256 + tid;
            int key = c2 >> 5, f4 = c2 & 31;
            float4v vv = *(const float4v*)(vg + (size_t)(krow0 + key)*128 + f4*4);
            #pragma unroll
            for (int j = 0; j < 4; j++)
                vts[(f4*4 + j)*72 + key] = f2bf(vv[j]);
        }
        __syncthreads();

        float4v s4[4];
        #pragma unroll
        for (int nt = 0; nt < 4; nt++){
            float4v c = {0.f, 0.f, 0.f, 0.f};
            #pragma unroll
            for (int ks = 0; ks < 4; ks++){
                short8 bb = *(const short8*)(ksm + (nt*16 + lq)*136 + ks*32 + quad*8);
                c = __builtin_amdgcn_mfma_f32_16x16x32_bf16(qf[ks], bb, c, 0, 0, 0);
            }
            #pragma unroll
            for (int r = 0; r < 4; r++)
                c[r] = fminf(fmaxf(c[r], MASKV), 30000.0f);
            s4[nt] = c;
        }
        if (kt == qt){
            #pragma unroll
            for (int nt = 0; nt < 4; nt++)
                #pragma unroll
                for (int r = 0; r < 4; r++){
                    int ci = nt*16 + lq;
                    int ri = wave*16 + quad*4 + r;
                    if (ci > ri) s4[nt][r] = MASKV;
                }
        }
        float p[4][4];
        #pragma unroll
        for (int r = 0; r < 4; r++){
            float mx = fmaxf(fmaxf(s4[0][r], s4[1][r]), fmaxf(s4[2][r], s4[3][r]));
            mx = fmaxf(mx, __shfl_xor(mx, 1));
            mx = fmaxf(mx, __shfl_xor(mx, 2));
            mx = fmaxf(mx, __shfl_xor(mx, 4));
            mx = fmaxf(mx, __shfl_xor(mx, 8));
            float mnew = fmaxf(mrun[r], mx);
            float alpha = __expf(mrun[r] - mnew);
            float rs = 0.f;
            #pragma unroll
            for (int nt = 0; nt < 4; nt++){
                float pv = __expf(s4[nt][r] - mnew);
                p[nt][r] = pv;
                rs += pv;
            }
            rs += __shfl_xor(rs, 1);
            rs += __shfl_xor(rs, 2);
            rs += __shfl_xor(rs, 4);
            rs += __shfl_xor(rs, 8);
            lrun[r] = lrun[r] * alpha + rs;
            mrun[r] = mnew;
            #pragma unroll
            for (int o = 0; o < 8; o++) oacc[o][r] *= alpha;
        }
        #pragma unroll
        for (int nt = 0; nt < 4; nt++)
            #pragma unroll
            for (int r = 0; r < 4; r++)
                ps[wave*1152 + (quad*4 + r)*72 + nt*16 + lq] = f2bf(p[nt][r]);
        __syncthreads();
        #pragma unroll
        for (int k2 = 0; k2 < 2; k2++){
            short8 pa = *(const short8*)(ps + wave*1152 + lq*72 + k2*32 + quad*8);
            #pragma unroll
            for (int o = 0; o < 8; o++){
                short8 bb = *(const short8*)(vts + (o*16 + lq)*72 + k2*32 + quad*8);
                oacc[o] = __builtin_amdgcn_mfma_f32_16x16x32_bf16(pa, bb, oacc[o], 0, 0, 0);
            }
        }
    }
    #pragma unroll
    for (int r = 0; r < 4; r++){
        float inv = 1.0f / lrun[r];
        int row = qrow0 + wave*16 + quad*4 + r;
        #pragma unroll
        for (int o = 0; o < 8; o++)
            dout[(size_t)row * 128 + o*16 + lq] = oacc[o][r] * inv;
    }
}

extern "C" void kernel_launch(void* const* d_in, const int* in_sizes, int n_in,
                              void* d_out, int out_size, void* d_ws, size_t ws_size,
                              hipStream_t stream){
    const float* x  = (const float*)d_in[0];
    const float* Wk = (const float*)d_in[1];
    const float* Wq = (const float*)d_in[2];
    const float* Wv = (const float*)d_in[3];
    float* out = (float*)d_out;
    u16* WT = (u16*)d_ws;                         // 96 KB

    const size_t QOFF = 98304;                    // WT bytes
    const size_t TEN  = (size_t)BTH * 2;          // one bf16 tensor = 32 MiB
    const size_t NEED = QOFF + 3 * TEN;           // ~96.1 MiB

    wt_kernel<<<192, 256, 0, stream>>>(Wq, Wk, Wv, WT);

    if (ws_size >= NEED){
        u16* qws = (u16*)((char*)d_ws + QOFF);
        u16* kws = qws + (size_t)BTH;
        u16* vws = kws + (size_t)BTH;
        proj_kernel <<<2048, 256, 0, stream>>>(x, WT, out, qws, kws, vws);
        attn2_kernel<<<2048, 256, 0, stream>>>(qws, kws, vws, out);
    } else {
        kv_kernel  <<<2048, 256, 0, stream>>>(x, WT, out);
        attn_kernel<<<2048, 256, 0, stream>>>(x, WT, out);
    }
}

// Round 2
// 395.425 us; speedup vs baseline: 1.1023x; 1.1023x over previous
//
#include <hip/hip_runtime.h>

typedef unsigned short u16;
typedef __attribute__((ext_vector_type(8))) short short8;
typedef __attribute__((ext_vector_type(4))) short short4v;
typedef __attribute__((ext_vector_type(4))) float float4v;

#define BTH (512*256*128)   // elements per output tensor
#define MASKV (-30000.0f)

__device__ __forceinline__ u16 f2bf(float f){
    union{float f; unsigned i;} v; v.f = f;
    unsigned x = v.i;
    unsigned r = (x + 0x7FFFu + ((x >> 16) & 1u)) >> 16;  // RNE
    return (u16)r;
}
__device__ __forceinline__ void store4bf(u16* dst, float4v v){
    short4v s = { (short)f2bf(v[0]), (short)f2bf(v[1]), (short)f2bf(v[2]), (short)f2bf(v[3]) };
    *(short4v*)dst = s;   // 8B aligned at all call sites
}

// ---------------- Kernel 0: f32 weights -> bf16 WT[3][128 n][128 k] in ws; fold C^-0.5 into Wq.
__global__ void wt_kernel(const float* __restrict__ Wq, const float* __restrict__ Wk,
                          const float* __restrict__ Wv, u16* __restrict__ WT){
    int idx = blockIdx.x * 256 + threadIdx.x;   // 0..49151
    int w   = idx >> 14;
    int rem = idx & 16383;
    int n = rem >> 7;
    int k = rem & 127;
    const float* src = (w == 0) ? Wq : (w == 1) ? Wk : Wv;
    float val = src[k * 128 + n];
    if (w == 0) val *= 0.08838834764831845f;    // 128^-0.5
    WT[idx] = f2bf(val);
}

// ============================================================================
// proj: q/k/v = x @ W per 64-row block.  All epilogues repacked through
// per-wave LDS -> vectorized coalesced global stores (was 160 scalar stores).
//   q  -> bf16 ws              k -> f32 out + bf16 ws
//   v  -> f32 out              vT -> bf16 ws [b][h][t]  (swapped MFMA)
// ============================================================================
__global__ __launch_bounds__(256) void proj_kernel(const float* __restrict__ x,
                                                   const u16* __restrict__ WT,
                                                   float* __restrict__ dout,
                                                   u16* __restrict__ qws,
                                                   u16* __restrict__ kws,
                                                   u16* __restrict__ vws){
    // xs (17408B) overlaps waves 0/1's rp regions; barrier separates the uses.
    __shared__ unsigned char smem[4 * 9216];
    u16* xs = (u16*)smem;                       // [64][136] bf16 x tile
    int row0 = blockIdx.x * 64;
    int tid = threadIdx.x;
    int wave = tid >> 6, lane = tid & 63, lq = lane & 15, quad = lane >> 4;
    float* rp_f32 = (float*)(smem + wave * 9216);   // [64][36] f32, stride 144B
    u16*   rp_u16 = (u16*)  (smem + wave * 9216);   // [64][72] u16, stride 144B
    int gn0 = wave * 32;

    // stage x rows (f32 -> bf16), coalesced
    #pragma unroll
    for (int g = 0; g < 8; g++){
        int c2 = g*256 + tid;
        int r = c2 >> 5, f4 = c2 & 31;
        float4v xx = *(const float4v*)(x + (size_t)(row0 + r)*128 + f4*4);
        store4bf(xs + r*136 + f4*4, xx);
    }
    __syncthreads();

    // A-frags: full 64-row tile per wave
    short8 a[4][4];
    #pragma unroll
    for (int mt = 0; mt < 4; mt++)
        #pragma unroll
        for (int ks = 0; ks < 4; ks++)
            a[mt][ks] = *(const short8*)(xs + (mt*16 + lq)*136 + ks*32 + quad*8);
    __syncthreads();   // xs dead; rp regions may now be written

    // ---- Q: bf16 tile -> LDS -> 4x 16B stores
    #pragma unroll
    for (int nt2 = 0; nt2 < 2; nt2++){
        short8 bw[4];
        #pragma unroll
        for (int ks = 0; ks < 4; ks++)
            bw[ks] = *(const short8*)(WT + (size_t)(gn0 + nt2*16 + lq)*128 + ks*32 + quad*8);
        #pragma unroll
        for (int mt = 0; mt < 4; mt++){
            float4v c = {0.f, 0.f, 0.f, 0.f};
            #pragma unroll
            for (int ks = 0; ks < 4; ks++)
                c = __builtin_amdgcn_mfma_f32_16x16x32_bf16(a[mt][ks], bw[ks], c, 0, 0, 0);
            #pragma unroll
            for (int r = 0; r < 4; r++)
                rp_u16[(mt*16 + quad*4 + r)*72 + nt2*16 + lq] = f2bf(c[r]);
        }
    }
    #pragma unroll
    for (int g = 0; g < 4; g++){
        int idx = g*64 + lane;
        int row = idx >> 2, c = idx & 3;
        short8 s = *(const short8*)(rp_u16 + row*72 + c*8);
        *(short8*)(qws + (size_t)(row0 + row)*128 + gn0 + c*8) = s;
    }

    // ---- K: f32 tile -> LDS -> f32 out (8x 16B) + bf16 ws (8x 8B)
    #pragma unroll
    for (int nt2 = 0; nt2 < 2; nt2++){
        short8 bw[4];
        #pragma unroll
        for (int ks = 0; ks < 4; ks++)
            bw[ks] = *(const short8*)(WT + (size_t)16384 + (size_t)(gn0 + nt2*16 + lq)*128 + ks*32 + quad*8);
        #pragma unroll
        for (int mt = 0; mt < 4; mt++){
            float4v c = {0.f, 0.f, 0.f, 0.f};
            #pragma unroll
            for (int ks = 0; ks < 4; ks++)
                c = __builtin_amdgcn_mfma_f32_16x16x32_bf16(a[mt][ks], bw[ks], c, 0, 0, 0);
            #pragma unroll
            for (int r = 0; r < 4; r++)
                rp_f32[(mt*16 + quad*4 + r)*36 + nt2*16 + lq] = c[r];
        }
    }
    #pragma unroll
    for (int g = 0; g < 8; g++){
        int idx = g*64 + lane;
        int row = idx >> 3, c4 = idx & 7;
        float4v f = *(const float4v*)(rp_f32 + row*36 + c4*4);
        *(float4v*)(dout + (size_t)BTH + (size_t)(row0 + row)*128 + gn0 + c4*4) = f;
        short4v s = { (short)f2bf(f[0]), (short)f2bf(f[1]), (short)f2bf(f[2]), (short)f2bf(f[3]) };
        *(short4v*)(kws + (size_t)(row0 + row)*128 + gn0 + c4*4) = s;
    }

    // ---- V: f32 tile -> LDS -> f32 out (8x 16B)
    #pragma unroll
    for (int nt2 = 0; nt2 < 2; nt2++){
        short8 bw[4];
        #pragma unroll
        for (int ks = 0; ks < 4; ks++)
            bw[ks] = *(const short8*)(WT + (size_t)2*16384 + (size_t)(gn0 + nt2*16 + lq)*128 + ks*32 + quad*8);
        #pragma unroll
        for (int mt = 0; mt < 4; mt++){
            float4v c = {0.f, 0.f, 0.f, 0.f};
            #pragma unroll
            for (int ks = 0; ks < 4; ks++)
                c = __builtin_amdgcn_mfma_f32_16x16x32_bf16(a[mt][ks], bw[ks], c, 0, 0, 0);
            #pragma unroll
            for (int r = 0; r < 4; r++)
                rp_f32[(mt*16 + quad*4 + r)*36 + nt2*16 + lq] = c[r];
        }
    }
    #pragma unroll
    for (int g = 0; g < 8; g++){
        int idx = g*64 + lane;
        int row = idx >> 3, c4 = idx & 7;
        float4v f = *(const float4v*)(rp_f32 + row*36 + c4*4);
        *(float4v*)(dout + (size_t)2*BTH + (size_t)(row0 + row)*128 + gn0 + c4*4) = f;
    }

    // ---- V^T: swapped MFMA (A = WvT rows, B = x rows). 32 h-rows x 64 t-cols per wave.
    {
        int b = row0 >> 8, t0 = row0 & 255;
        int gh0 = wave * 32;
        #pragma unroll
        for (int mt2 = 0; mt2 < 2; mt2++){
            short8 av[4];
            #pragma unroll
            for (int ks = 0; ks < 4; ks++)
                av[ks] = *(const short8*)(WT + (size_t)2*16384 + (size_t)(gh0 + mt2*16 + lq)*128 + ks*32 + quad*8);
            #pragma unroll
            for (int nt = 0; nt < 4; nt++){
                float4v c = {0.f, 0.f, 0.f, 0.f};
                #pragma unroll
                for (int ks = 0; ks < 4; ks++)
                    c = __builtin_amdgcn_mfma_f32_16x16x32_bf16(av[ks], a[nt][ks], c, 0, 0, 0);
                #pragma unroll
                for (int r = 0; r < 4; r++)
                    rp_u16[(mt2*16 + quad*4 + r)*72 + nt*16 + lq] = f2bf(c[r]);
            }
        }
        #pragma unroll
        for (int g = 0; g < 4; g++){
            int idx = g*64 + lane;
            int row = idx >> 3, c = idx & 7;          // 32 rows x 8 chunks
            short8 s = *(const short8*)(rp_u16 + row*72 + c*8);
            *(short8*)(vws + ((size_t)b*128 + gh0 + row)*256 + t0 + c*8) = s;
        }
    }
}

// ============================================================================
// attn3: barrier-free flash attention, balanced blocks.
// Each block handles q-tile pair (qt, 3-qt) of one batch -> exactly 5
// kt-iterations per block.  1024 uniform blocks.  V k2=0 fragment loads
// issued before softmax to hide global latency under the VALU burst.
// ============================================================================
__global__ __launch_bounds__(256) void attn3_kernel(const u16* __restrict__ qws,
                                                    const u16* __restrict__ kws,
                                                    const u16* __restrict__ vws,
                                                    float* __restrict__ dout){
    __shared__ u16 ps[4 * 16 * 72];  // per-wave P buffer [16 rows][64 keys]

    // XCD-chunked swizzle (1024 = 8*128): batch's 2 blocks land adjacent on one XCD
    int lb = ((blockIdx.x & 7) << 7) | (blockIdx.x >> 3);
    int b = lb >> 1, pair = lb & 1;
    int tid = threadIdx.x;
    int wave = tid >> 6, lane = tid & 63, lq = lane & 15, quad = lane >> 4;

    #pragma unroll
    for (int qs = 0; qs < 2; qs++){
        int qt = (qs == 0) ? pair : (3 - pair);   // {0,3} or {1,2}
        int qrow = b*256 + qt*64 + wave*16;

        short8 qf[4];
        #pragma unroll
        for (int ks = 0; ks < 4; ks++)
            qf[ks] = *(const short8*)(qws + (size_t)(qrow + lq)*128 + ks*32 + quad*8);

        float4v oacc[8];
        #pragma unroll
        for (int i = 0; i < 8; i++) oacc[i] = (float4v){0.f, 0.f, 0.f, 0.f};
        float mrun[4] = {MASKV, MASKV, MASKV, MASKV};
        float lrun[4] = {0.f, 0.f, 0.f, 0.f};

        for (int kt = 0; kt <= qt; kt++){
            const u16* kp = kws + ((size_t)b*256 + kt*64)*128;   // K rows [key][h]
            const u16* vp = vws + (size_t)b*128*256 + kt*64;     // V^T rows [h][t]

            // S = Q K^T : wave's 16 rows x 64 keys
            float4v s4[4];
            #pragma unroll
            for (int nt = 0; nt < 4; nt++){
                float4v c = {0.f, 0.f, 0.f, 0.f};
                #pragma unroll
                for (int ks = 0; ks < 4; ks++){
                    short8 bb = *(const short8*)(kp + (size_t)(nt*16 + lq)*128 + ks*32 + quad*8);
                    c = __builtin_amdgcn_mfma_f32_16x16x32_bf16(qf[ks], bb, c, 0, 0, 0);
                }
                #pragma unroll
                for (int r = 0; r < 4; r++)
                    c[r] = fminf(fmaxf(c[r], MASKV), 30000.0f);   // NaN/inf scrub insurance
                s4[nt] = c;
            }

            // prefetch V (k2=0 half) -- independent of softmax, hides latency
            short8 vb0[8];
            #pragma unroll
            for (int o = 0; o < 8; o++)
                vb0[o] = *(const short8*)(vp + (size_t)(o*16 + lq)*256 + quad*8);

            if (kt == qt){
                #pragma unroll
                for (int nt = 0; nt < 4; nt++)
                    #pragma unroll
                    for (int r = 0; r < 4; r++){
                        int ci = nt*16 + lq;
                        int ri = wave*16 + quad*4 + r;
                        if (ci > ri) s4[nt][r] = MASKV;
                    }
            }
            // online softmax (quad's 16 lanes hold one row's 64 cols)
            float p[4][4];
            #pragma unroll
            for (int r = 0; r < 4; r++){
                float mx = fmaxf(fmaxf(s4[0][r], s4[1][r]), fmaxf(s4[2][r], s4[3][r]));
                mx = fmaxf(mx, __shfl_xor(mx, 1));
                mx = fmaxf(mx, __shfl_xor(mx, 2));
                mx = fmaxf(mx, __shfl_xor(mx, 4));
                mx = fmaxf(mx, __shfl_xor(mx, 8));
                float mnew = fmaxf(mrun[r], mx);
                float alpha = __expf(mrun[r] - mnew);
                float rs = 0.f;
                #pragma unroll
                for (int nt = 0; nt < 4; nt++){
                    float pv = __expf(s4[nt][r] - mnew);
                    p[nt][r] = pv;
                    rs += pv;
                }
                rs += __shfl_xor(rs, 1);
                rs += __shfl_xor(rs, 2);
                rs += __shfl_xor(rs, 4);
                rs += __shfl_xor(rs, 8);
                lrun[r] = lrun[r] * alpha + rs;
                mrun[r] = mnew;
                #pragma unroll
                for (int o = 0; o < 8; o++) oacc[o][r] *= alpha;
            }
            // P: C/D-layout -> per-wave LDS -> A-layout (same-wave, no barrier)
            #pragma unroll
            for (int nt = 0; nt < 4; nt++)
                #pragma unroll
                for (int r = 0; r < 4; r++)
                    ps[wave*1152 + (quad*4 + r)*72 + nt*16 + lq] = f2bf(p[nt][r]);
            short8 pa0 = *(const short8*)(ps + wave*1152 + lq*72 + quad*8);
            short8 pa1 = *(const short8*)(ps + wave*1152 + lq*72 + 32 + quad*8);
            // O += P V  (k2=0 uses prefetched frags; k2=1 loads inline)
            #pragma unroll
            for (int o = 0; o < 8; o++)
                oacc[o] = __builtin_amdgcn_mfma_f32_16x16x32_bf16(pa0, vb0[o], oacc[o], 0, 0, 0);
            #pragma unroll
            for (int o = 0; o < 8; o++){
                short8 vb1 = *(const short8*)(vp + (size_t)(o*16 + lq)*256 + 32 + quad*8);
                oacc[o] = __builtin_amdgcn_mfma_f32_16x16x32_bf16(pa1, vb1, oacc[o], 0, 0, 0);
            }
        }
        // epilogue: out f32
        #pragma unroll
        for (int r = 0; r < 4; r++){
            float inv = 1.0f / lrun[r];
            int row = qrow + quad*4 + r;
            #pragma unroll
            for (int o = 0; o < 8; o++)
                dout[(size_t)row * 128 + o*16 + lq] = oacc[o][r] * inv;
        }
    }
}

// ============================================================================
// FALLBACK PATH (verified round-0 kernels) — used if workspace too small.
// ============================================================================

__global__ __launch_bounds__(256) void kv_kernel(const float* __restrict__ x,
                                                 const u16* __restrict__ WT,
                                                 float* __restrict__ dout){
    int row0 = blockIdx.x * 64;
    int tid = threadIdx.x;
    int wave = tid >> 6, lane = tid & 63, lq = lane & 15, quad = lane >> 4;

    short8 a[4][4];
    #pragma unroll
    for (int mt = 0; mt < 4; mt++)
        #pragma unroll
        for (int ks = 0; ks < 4; ks++){
            const float* px = x + (size_t)(row0 + mt*16 + lq)*128 + ks*32 + quad*8;
            float4v lo = *(const float4v*)px;
            float4v hi = *(const float4v*)(px + 4);
            short8 s;
            #pragma unroll
            for (int j = 0; j < 4; j++){
                s[j]     = (short)f2bf(lo[j]);
                s[j + 4] = (short)f2bf(hi[j]);
            }
            a[mt][ks] = s;
        }

    #pragma unroll
    for (int nt4 = 0; nt4 < 4; nt4++){
        int gn = wave*64 + nt4*16;
        short8 bfrag[4];
        #pragma unroll
        for (int ks = 0; ks < 4; ks++)
            bfrag[ks] = *(const short8*)(WT + (size_t)(128 + gn + lq)*128 + ks*32 + quad*8);
        float* outp = dout + (size_t)(1 + (gn >> 7)) * BTH;
        int h = (gn & 127) + lq;
        #pragma unroll
        for (int mt = 0; mt < 4; mt++){
            float4v c = {0.f, 0.f, 0.f, 0.f};
            #pragma unroll
            for (int ks = 0; ks < 4; ks++)
                c = __builtin_amdgcn_mfma_f32_16x16x32_bf16(a[mt][ks], bfrag[ks], c, 0, 0, 0);
            int rowb = row0 + mt*16 + quad*4;
            #pragma unroll
            for (int r = 0; r < 4; r++)
                outp[(size_t)(rowb + r) * 128 + h] = c[r];
        }
    }
}

__global__ __launch_bounds__(256) void attn_kernel(const float* __restrict__ x,
                                                   const u16* __restrict__ WT,
                                                   float* __restrict__ dout){
    const float* kg = dout + (size_t)BTH;
    const float* vg = dout + (size_t)2 * BTH;

    __shared__ u16 ksm[64 * 136];
    __shared__ u16 qsm[64 * 136];
    __shared__ u16 vts[128 * 72];
    __shared__ u16 ps [4 * 16 * 72];

    int blk = blockIdx.x;
    int b = blk >> 2, qt = blk & 3;
    int tid = threadIdx.x;
    int wave = tid >> 6, lane = tid & 63, lq = lane & 15, quad = lane >> 4;
    int qrow0 = b * 256 + qt * 64;

    #pragma unroll
    for (int g = 0; g < 8; g++){
        int c2 = g*256 + tid;
        int r = c2 >> 5, f4 = c2 & 31;
        float4v xx = *(const float4v*)(x + (size_t)(qrow0 + r)*128 + f4*4);
        store4bf(ksm + r*136 + f4*4, xx);
    }
    __syncthreads();
    {
        short8 ax[4];
        #pragma unroll
        for (int ks = 0; ks < 4; ks++)
            ax[ks] = *(const short8*)(ksm + (wave*16 + lq)*136 + ks*32 + quad*8);
        #pragma unroll
        for (int nt8 = 0; nt8 < 8; nt8++){
            short8 bq[4];
            #pragma unroll
            for (int ks = 0; ks < 4; ks++)
                bq[ks] = *(const short8*)(WT + (size_t)(nt8*16 + lq)*128 + ks*32 + quad*8);
            float4v c = {0.f, 0.f, 0.f, 0.f};
            #pragma unroll
            for (int ks = 0; ks < 4; ks++)
                c = __builtin_amdgcn_mfma_f32_16x16x32_bf16(ax[ks], bq[ks], c, 0, 0, 0);
            #pragma unroll
            for (int r = 0; r < 4; r++)
                qsm[(wave*16 + quad*4 + r)*136 + nt8*16 + lq] = f2bf(c[r]);
        }
    }
    __syncthreads();
    short8 qf[4];
    #pragma unroll
    for (int ks = 0; ks < 4; ks++)
        qf[ks] = *(const short8*)(qsm + (wave*16 + lq)*136 + ks*32 + quad*8);

    float4v oacc[8];
    #pragma unroll
    for (int i = 0; i < 8; i++) oacc[i] = (float4v){0.f, 0.f, 0.f, 0.f};
    float mrun[4] = {MASKV, MASKV, MASKV, MASKV};
    float lrun[4] = {0.f, 0.f, 0.f, 0.f};

    for (int kt = 0; kt <= qt; kt++){
        int krow0 = b * 256 + kt * 64;
        __syncthreads();
        #pragma unroll
        for (int g = 0; g < 8; g++){
            int c2 = g*256 + tid;
            int r = c2 >> 5, f4 = c2 & 31;
            float4v kk = *(const float4v*)(kg + (size_t)(krow0 + r)*128 + f4*4);
            store4bf(ksm + r*136 + f4*4, kk);
        }
        #pragma unroll
        for (int g = 0; g < 8; g++){
            int c2 = g*256 + tid;
            int key = c2 >> 5, f4 = c2 & 31;
            float4v vv = *(const float4v*)(vg + (size_t)(krow0 + key)*128 + f4*4);
            #pragma unroll
            for (int j = 0; j < 4; j++)
                vts[(f4*4 + j)*72 + key] = f2bf(vv[j]);
        }
        __syncthreads();

        float4v s4[4];
        #pragma unroll
        for (int nt = 0; nt < 4; nt++){
            float4v c = {0.f, 0.f, 0.f, 0.f};
            #pragma unroll
            for (int ks = 0; ks < 4; ks++){
                short8 bb = *(const short8*)(ksm + (nt*16 + lq)*136 + ks*32 + quad*8);
                c = __builtin_amdgcn_mfma_f32_16x16x32_bf16(qf[ks], bb, c, 0, 0, 0);
            }
            #pragma unroll
            for (int r = 0; r < 4; r++)
                c[r] = fminf(fmaxf(c[r], MASKV), 30000.0f);
            s4[nt] = c;
        }
        if (kt == qt){
            #pragma unroll
            for (int nt = 0; nt < 4; nt++)
                #pragma unroll
                for (int r = 0; r < 4; r++){
                    int ci = nt*16 + lq;
                    int ri = wave*16 + quad*4 + r;
                    if (ci > ri) s4[nt][r] = MASKV;
                }
        }
        float p[4][4];
        #pragma unroll
        for (int r = 0; r < 4; r++){
            float mx = fmaxf(fmaxf(s4[0][r], s4[1][r]), fmaxf(s4[2][r], s4[3][r]));
            mx = fmaxf(mx, __shfl_xor(mx, 1));
            mx = fmaxf(mx, __shfl_xor(mx, 2));
            mx = fmaxf(mx, __shfl_xor(mx, 4));
            mx = fmaxf(mx, __shfl_xor(mx, 8));
            float mnew = fmaxf(mrun[r], mx);
            float alpha = __expf(mrun[r] - mnew);
            float rs = 0.f;
            #pragma unroll
            for (int nt = 0; nt < 4; nt++){
                float pv = __expf(s4[nt][r] - mnew);
                p[nt][r] = pv;
                rs += pv;
            }
            rs += __shfl_xor(rs, 1);
            rs += __shfl_xor(rs, 2);
            rs += __shfl_xor(rs, 4);
            rs += __shfl_xor(rs, 8);
            lrun[r] = lrun[r] * alpha + rs;
            mrun[r] = mnew;
            #pragma unroll
            for (int o = 0; o < 8; o++) oacc[o][r] *= alpha;
        }
        #pragma unroll
        for (int nt = 0; nt < 4; nt++)
            #pragma unroll
            for (int r = 0; r < 4; r++)
                ps[wave*1152 + (quad*4 + r)*72 + nt*16 + lq] = f2bf(p[nt][r]);
        __syncthreads();
        #pragma unroll
        for (int k2 = 0; k2 < 2; k2++){
            short8 pa = *(const short8*)(ps + wave*1152 + lq*72 + k2*32 + quad*8);
            #pragma unroll
            for (int o = 0; o < 8; o++){
                short8 bb = *(const short8*)(vts + (o*16 + lq)*72 + k2*32 + quad*8);
                oacc[o] = __builtin_amdgcn_mfma_f32_16x16x32_bf16(pa, bb, oacc[o], 0, 0, 0);
            }
        }
    }
    #pragma unroll
    for (int r = 0; r < 4; r++){
        float inv = 1.0f / lrun[r];
        int row = qrow0 + wave*16 + quad*4 + r;
        #pragma unroll
        for (int o = 0; o < 8; o++)
            dout[(size_t)row * 128 + o*16 + lq] = oacc[o][r] * inv;
    }
}

extern "C" void kernel_launch(void* const* d_in, const int* in_sizes, int n_in,
                              void* d_out, int out_size, void* d_ws, size_t ws_size,
                              hipStream_t stream){
    const float* x  = (const float*)d_in[0];
    const float* Wk = (const float*)d_in[1];
    const float* Wq = (const float*)d_in[2];
    const float* Wv = (const float*)d_in[3];
    float* out = (float*)d_out;
    u16* WT = (u16*)d_ws;                         // 96 KB

    const size_t QOFF = 98304;                    // WT bytes
    const size_t TEN  = (size_t)BTH * 2;          // one bf16 tensor = 32 MiB
    const size_t NEED = QOFF + 3 * TEN;           // ~96.1 MiB

    wt_kernel<<<192, 256, 0, stream>>>(Wq, Wk, Wv, WT);

    if (ws_size >= NEED){
        u16* qws = (u16*)((char*)d_ws + QOFF);
        u16* kws = qws + (size_t)BTH;
        u16* vws = kws + (size_t)BTH;
        proj_kernel <<<2048, 256, 0, stream>>>(x, WT, out, qws, kws, vws);
        attn3_kernel<<<1024, 256, 0, stream>>>(qws, kws, vws, out);
    } else {
        kv_kernel  <<<2048, 256, 0, stream>>>(x, WT, out);
        attn_kernel<<<2048, 256, 0, stream>>>(x, WT, out);
    }
}

// Round 3
// 328.558 us; speedup vs baseline: 1.3266x; 1.2035x over previous
//
#include <hip/hip_runtime.h>

typedef unsigned short u16;
typedef __attribute__((ext_vector_type(8))) short short8;
typedef __attribute__((ext_vector_type(4))) short short4v;
typedef __attribute__((ext_vector_type(4))) float float4v;

#define BTH (512*256*128)   // elements per output tensor
#define MASKV (-30000.0f)

__device__ __forceinline__ u16 f2bf(float f){
    union{float f; unsigned i;} v; v.f = f;
    unsigned x = v.i;
    unsigned r = (x + 0x7FFFu + ((x >> 16) & 1u)) >> 16;  // RNE
    return (u16)r;
}
__device__ __forceinline__ void store4bf(u16* dst, float4v v){
    short4v s = { (short)f2bf(v[0]), (short)f2bf(v[1]), (short)f2bf(v[2]), (short)f2bf(v[3]) };
    *(short4v*)dst = s;   // 8B aligned at all call sites
}

// async global->LDS, 16B per lane.  LDS dest is wave-uniform; HW adds lane*16.
__device__ __forceinline__ void gll16(const void* g, void* l){
    __builtin_amdgcn_global_load_lds(
        (__attribute__((address_space(1))) void*)(unsigned long long)g,
        (__attribute__((address_space(3))) void*)(unsigned)(unsigned long long)l,
        16, 0, 0);
}
// copy one 16KB tile (8192 u16) global->LDS; 4 insts per wave (this wave's quarter)
__device__ __forceinline__ void stage_tile(const u16* gtile, u16* ltile, int wave, int lane){
    const u16* g = gtile + wave*2048 + lane*8;
    u16* l = ltile + wave*2048;
    gll16(g,        l);
    gll16(g + 512,  l + 512);
    gll16(g + 1024, l + 1024);
    gll16(g + 1536, l + 1536);
}

// ---------------- Kernel 0: f32 weights -> bf16 WT[3][128 n][128 k]; fold C^-0.5 into Wq.
__global__ void wt_kernel(const float* __restrict__ Wq, const float* __restrict__ Wk,
                          const float* __restrict__ Wv, u16* __restrict__ WT){
    int idx = blockIdx.x * 256 + threadIdx.x;   // 0..49151
    int w   = idx >> 14;
    int rem = idx & 16383;
    int n = rem >> 7;
    int k = rem & 127;
    const float* src = (w == 0) ? Wq : (w == 1) ? Wk : Wv;
    float val = src[k * 128 + n];
    if (w == 0) val *= 0.08838834764831845f;    // 128^-0.5
    WT[idx] = f2bf(val);
}

// ============================================================================
// proj: q/k/v = x @ W per 64-row block (= one attention K/V tile).
//   q  -> bf16 ws [t][h]
//   k  -> f32 out + bf16 ws in PERMUTED tile layout (see below)
//   v  -> f32 out; vT -> bf16 ws in PERMUTED tile layout (swapped MFMA)
// Permuted K tile  (8192 u16): e = ks*2048 + row*32 + (col-32*ks)        col=ks*32+qd*8+j
// Permuted VT tile (8192 u16): e = k2*4096 + h*32 + (t-32*k2)            t =k2*32+qd*8+j
// These make attn's LDS image linear for global_load_lds AND its
// ds_read_b128 fragment reads contiguous-1KB (conflict-free).
// ============================================================================
__global__ __launch_bounds__(256) void proj_kernel(const float* __restrict__ x,
                                                   const u16* __restrict__ WT,
                                                   float* __restrict__ dout,
                                                   u16* __restrict__ qws,
                                                   u16* __restrict__ kws,
                                                   u16* __restrict__ vws){
    __shared__ u16 xs[64 * 152];                 // 19456 B, stride-152 (~2-way on frag reads)
    __shared__ unsigned char rps[4 * 4608];      // per-wave half-tile repack
    int row0 = blockIdx.x * 64;
    int tid = threadIdx.x;
    int wave = tid >> 6, lane = tid & 63, lq = lane & 15, quad = lane >> 4;
    float* rp_f = (float*)(rps + wave * 4608);   // [32][36] f32
    u16*   rp_h = (u16*)  (rps + wave * 4608);   // [32][72] u16
    int w = wave;
    int b = row0 >> 8, kt = (row0 >> 6) & 3;
    size_t tbase = ((size_t)b * 4 + kt) * 8192;

    // stage x rows (f32 -> bf16), coalesced
    #pragma unroll
    for (int g = 0; g < 8; g++){
        int c2 = g*256 + tid;
        int r = c2 >> 5, f4 = c2 & 31;
        float4v xx = *(const float4v*)(x + (size_t)(row0 + r)*128 + f4*4);
        store4bf(xs + r*152 + f4*4, xx);
    }
    __syncthreads();

    short8 bw[2][4];

    // ---- Q: bf16 -> qws [t][h]
    #pragma unroll
    for (int nt2 = 0; nt2 < 2; nt2++)
        #pragma unroll
        for (int ks = 0; ks < 4; ks++)
            bw[nt2][ks] = *(const short8*)(WT + (size_t)(w*32 + nt2*16 + lq)*128 + ks*32 + quad*8);
    #pragma unroll
    for (int h = 0; h < 2; h++){
        short8 ah[2][4];
        #pragma unroll
        for (int mt2 = 0; mt2 < 2; mt2++)
            #pragma unroll
            for (int ks = 0; ks < 4; ks++)
                ah[mt2][ks] = *(const short8*)(xs + (h*32 + mt2*16 + lq)*152 + ks*32 + quad*8);
        #pragma unroll
        for (int nt2 = 0; nt2 < 2; nt2++)
            #pragma unroll
            for (int mt2 = 0; mt2 < 2; mt2++){
                float4v c = {0.f,0.f,0.f,0.f};
                #pragma unroll
                for (int ks = 0; ks < 4; ks++)
                    c = __builtin_amdgcn_mfma_f32_16x16x32_bf16(ah[mt2][ks], bw[nt2][ks], c, 0, 0, 0);
                #pragma unroll
                for (int r = 0; r < 4; r++)
                    rp_h[(mt2*16 + quad*4 + r)*72 + nt2*16 + lq] = f2bf(c[r]);
            }
        #pragma unroll
        for (int g = 0; g < 2; g++){
            int idx = g*64 + lane;
            int rowL = idx >> 2, c8 = idx & 3;
            short8 sv = *(const short8*)(rp_h + rowL*72 + c8*8);
            *(short8*)(qws + (size_t)(row0 + h*32 + rowL)*128 + w*32 + c8*8) = sv;
        }
    }

    // ---- K: f32 out + bf16 permuted ws
    #pragma unroll
    for (int nt2 = 0; nt2 < 2; nt2++)
        #pragma unroll
        for (int ks = 0; ks < 4; ks++)
            bw[nt2][ks] = *(const short8*)(WT + (size_t)16384 + (size_t)(w*32 + nt2*16 + lq)*128 + ks*32 + quad*8);
    #pragma unroll
    for (int h = 0; h < 2; h++){
        short8 ah[2][4];
        #pragma unroll
        for (int mt2 = 0; mt2 < 2; mt2++)
            #pragma unroll
            for (int ks = 0; ks < 4; ks++)
                ah[mt2][ks] = *(const short8*)(xs + (h*32 + mt2*16 + lq)*152 + ks*32 + quad*8);
        #pragma unroll
        for (int nt2 = 0; nt2 < 2; nt2++)
            #pragma unroll
            for (int mt2 = 0; mt2 < 2; mt2++){
                float4v c = {0.f,0.f,0.f,0.f};
                #pragma unroll
                for (int ks = 0; ks < 4; ks++)
                    c = __builtin_amdgcn_mfma_f32_16x16x32_bf16(ah[mt2][ks], bw[nt2][ks], c, 0, 0, 0);
                #pragma unroll
                for (int r = 0; r < 4; r++)
                    rp_f[(mt2*16 + quad*4 + r)*36 + nt2*16 + lq] = c[r];
            }
        #pragma unroll
        for (int g = 0; g < 4; g++){
            int idx = g*64 + lane;
            int rowL = idx >> 3, c4 = idx & 7;
            float4v f = *(const float4v*)(rp_f + rowL*36 + c4*4);
            *(float4v*)(dout + (size_t)BTH + (size_t)(row0 + h*32 + rowL)*128 + w*32 + c4*4) = f;
        }
        #pragma unroll
        for (int g = 0; g < 2; g++){
            int idx = g*64 + lane;
            int rowL = idx >> 2, c8 = idx & 3;
            float4v lo = *(const float4v*)(rp_f + rowL*36 + c8*8);
            float4v hi = *(const float4v*)(rp_f + rowL*36 + c8*8 + 4);
            short8 sv;
            #pragma unroll
            for (int j = 0; j < 4; j++){
                sv[j]   = (short)f2bf(lo[j]);
                sv[j+4] = (short)f2bf(hi[j]);
            }
            *(short8*)(kws + tbase + w*2048 + (size_t)(h*32 + rowL)*32 + c8*8) = sv;
        }
    }

    // ---- V: f32 out only
    #pragma unroll
    for (int nt2 = 0; nt2 < 2; nt2++)
        #pragma unroll
        for (int ks = 0; ks < 4; ks++)
            bw[nt2][ks] = *(const short8*)(WT + (size_t)2*16384 + (size_t)(w*32 + nt2*16 + lq)*128 + ks*32 + quad*8);
    #pragma unroll
    for (int h = 0; h < 2; h++){
        short8 ah[2][4];
        #pragma unroll
        for (int mt2 = 0; mt2 < 2; mt2++)
            #pragma unroll
            for (int ks = 0; ks < 4; ks++)
                ah[mt2][ks] = *(const short8*)(xs + (h*32 + mt2*16 + lq)*152 + ks*32 + quad*8);
        #pragma unroll
        for (int nt2 = 0; nt2 < 2; nt2++)
            #pragma unroll
            for (int mt2 = 0; mt2 < 2; mt2++){
                float4v c = {0.f,0.f,0.f,0.f};
                #pragma unroll
                for (int ks = 0; ks < 4; ks++)
                    c = __builtin_amdgcn_mfma_f32_16x16x32_bf16(ah[mt2][ks], bw[nt2][ks], c, 0, 0, 0);
                #pragma unroll
                for (int r = 0; r < 4; r++)
                    rp_f[(mt2*16 + quad*4 + r)*36 + nt2*16 + lq] = c[r];
            }
        #pragma unroll
        for (int g = 0; g < 4; g++){
            int idx = g*64 + lane;
            int rowL = idx >> 3, c4 = idx & 7;
            float4v f = *(const float4v*)(rp_f + rowL*36 + c4*4);
            *(float4v*)(dout + (size_t)2*BTH + (size_t)(row0 + h*32 + rowL)*128 + w*32 + c4*4) = f;
        }
    }

    // ---- V^T: swapped MFMA, A = Wv^T rows (reuse bw!), B = x rows. 32 h x 64 t per wave.
    {
        short8 ax[4][4];
        #pragma unroll
        for (int nt = 0; nt < 4; nt++)
            #pragma unroll
            for (int ks = 0; ks < 4; ks++)
                ax[nt][ks] = *(const short8*)(xs + (nt*16 + lq)*152 + ks*32 + quad*8);
        #pragma unroll
        for (int mt2 = 0; mt2 < 2; mt2++)
            #pragma unroll
            for (int nt = 0; nt < 4; nt++){
                float4v c = {0.f,0.f,0.f,0.f};
                #pragma unroll
                for (int ks = 0; ks < 4; ks++)
                    c = __builtin_amdgcn_mfma_f32_16x16x32_bf16(bw[mt2][ks], ax[nt][ks], c, 0, 0, 0);
                #pragma unroll
                for (int r = 0; r < 4; r++)
                    rp_h[(mt2*16 + quad*4 + r)*72 + nt*16 + lq] = f2bf(c[r]);
            }
        #pragma unroll
        for (int g = 0; g < 4; g++){
            int idx = g*64 + lane;
            int hL = idx >> 3, c = idx & 7;          // 32 h-rows x 8 chunks
            short8 sv = *(const short8*)(rp_h + hL*72 + c*8);
            *(short8*)(vws + tbase + (size_t)(c>>2)*4096 + (size_t)(w*32 + hL)*32 + (c&3)*8) = sv;
        }
    }
}

// ============================================================================
// attn4: flash attention with async LDS staging.
// K double-buffered, V single-buffered via global_load_lds (zero-VGPR staging);
// raw s_barrier + counted vmcnt keeps next-K prefetch in flight across barriers.
// Balanced: block handles q-tile pair (qt, 3-qt) -> exactly 5 iterations.
// ============================================================================
__global__ __launch_bounds__(256) void attn4_kernel(const u16* __restrict__ qws,
                                                    const u16* __restrict__ kws,
                                                    const u16* __restrict__ vws,
                                                    float* __restrict__ dout){
    __shared__ u16 kbufs[2 * 8192];  // 32 KB
    __shared__ u16 vbuf[8192];       // 16 KB
    __shared__ u16 ps[4 * 16 * 72];  // 9216 B  (total 58368 -> 2 blocks/CU)

    // XCD-chunked swizzle (1024 = 8*128)
    int lb = ((blockIdx.x & 7) << 7) | (blockIdx.x >> 3);
    int b = lb >> 1, pair = lb & 1;
    int tid = threadIdx.x;
    int wave = tid >> 6, lane = tid & 63, lq = lane & 15, quad = lane >> 4;

    const u16* ktiles = kws + (size_t)b * 4 * 8192;
    const u16* vtiles = vws + (size_t)b * 4 * 8192;

    // prologue: stage K tile 0 into kbuf 0
    stage_tile(ktiles, kbufs, wave, lane);
    asm volatile("s_waitcnt vmcnt(0)" ::: "memory");
    __builtin_amdgcn_s_barrier();

    int cur = 0;
    int qt = pair;
    int qrow = b*256 + qt*64 + wave*16;
    short8 qf[4];
    #pragma unroll
    for (int ks = 0; ks < 4; ks++)
        qf[ks] = *(const short8*)(qws + (size_t)(qrow + lq)*128 + ks*32 + quad*8);

    float4v oacc[8];
    #pragma unroll
    for (int i = 0; i < 8; i++) oacc[i] = (float4v){0.f,0.f,0.f,0.f};
    float mrun[4] = {MASKV, MASKV, MASKV, MASKV};
    float lrun[4] = {0.f, 0.f, 0.f, 0.f};

    for (int i = 0; i < 5; i++){
        int kt = (i <= pair) ? i : (i - pair - 1);

        // issue V(kt) stage (vbuf free: all waves passed end-of-prev barrier after PV)
        stage_tile(vtiles + (size_t)kt*8192, vbuf, wave, lane);
        // issue K(next) stage into the other buffer
        if (i < 4){
            int ktn = (i + 1 <= pair) ? (i + 1) : (i - pair);
            stage_tile(ktiles + (size_t)ktn*8192, kbufs + (cur^1)*8192, wave, lane);
        }

        const u16* kb = kbufs + cur*8192;
        // S = Q K^T : wave's 16 rows x 64 keys (conflict-free contiguous-1KB reads)
        float4v s4[4];
        __builtin_amdgcn_s_setprio(1);
        #pragma unroll
        for (int nt = 0; nt < 4; nt++){
            float4v c = {0.f,0.f,0.f,0.f};
            #pragma unroll
            for (int ks = 0; ks < 4; ks++){
                short8 bb = *(const short8*)(kb + ks*2048 + (nt*16 + lq)*32 + quad*8);
                c = __builtin_amdgcn_mfma_f32_16x16x32_bf16(qf[ks], bb, c, 0, 0, 0);
            }
            #pragma unroll
            for (int r = 0; r < 4; r++)
                c[r] = fminf(fmaxf(c[r], MASKV), 30000.0f);   // NaN/inf scrub insurance
            s4[nt] = c;
        }
        __builtin_amdgcn_s_setprio(0);
        if (kt == qt){
            #pragma unroll
            for (int nt = 0; nt < 4; nt++)
                #pragma unroll
                for (int r = 0; r < 4; r++){
                    int ci = nt*16 + lq;
                    int ri = wave*16 + quad*4 + r;
                    if (ci > ri) s4[nt][r] = MASKV;
                }
        }
        // online softmax (quad's 16 lanes hold one row's 64 cols)
        float p[4][4];
        #pragma unroll
        for (int r = 0; r < 4; r++){
            float mx = fmaxf(fmaxf(s4[0][r], s4[1][r]), fmaxf(s4[2][r], s4[3][r]));
            mx = fmaxf(mx, __shfl_xor(mx, 1));
            mx = fmaxf(mx, __shfl_xor(mx, 2));
            mx = fmaxf(mx, __shfl_xor(mx, 4));
            mx = fmaxf(mx, __shfl_xor(mx, 8));
            float mnew = fmaxf(mrun[r], mx);
            float alpha = __expf(mrun[r] - mnew);
            float rs = 0.f;
            #pragma unroll
            for (int nt = 0; nt < 4; nt++){
                float pv = __expf(s4[nt][r] - mnew);
                p[nt][r] = pv;
                rs += pv;
            }
            rs += __shfl_xor(rs, 1);
            rs += __shfl_xor(rs, 2);
            rs += __shfl_xor(rs, 4);
            rs += __shfl_xor(rs, 8);
            lrun[r] = lrun[r] * alpha + rs;
            mrun[r] = mnew;
            #pragma unroll
            for (int o = 0; o < 8; o++) oacc[o][r] *= alpha;
        }
        // drain V stage (4 oldest); keep next-K (4 newest) in flight
        if (i < 4) asm volatile("s_waitcnt vmcnt(4)" ::: "memory");
        else       asm volatile("s_waitcnt vmcnt(0)" ::: "memory");
        __builtin_amdgcn_sched_barrier(0);
        __builtin_amdgcn_s_barrier();       // all waves' V writes visible

        // P: C/D-layout -> per-wave LDS -> A-layout (same-wave ordering)
        #pragma unroll
        for (int nt = 0; nt < 4; nt++)
            #pragma unroll
            for (int r = 0; r < 4; r++)
                ps[wave*1152 + (quad*4 + r)*72 + nt*16 + lq] = f2bf(p[nt][r]);
        short8 pa0 = *(const short8*)(ps + wave*1152 + lq*72 + quad*8);
        short8 pa1 = *(const short8*)(ps + wave*1152 + lq*72 + 32 + quad*8);
        // O += P V
        __builtin_amdgcn_s_setprio(1);
        #pragma unroll
        for (int k2 = 0; k2 < 2; k2++){
            short8 pa = (k2 == 0) ? pa0 : pa1;
            #pragma unroll
            for (int o = 0; o < 8; o++){
                short8 bb = *(const short8*)(vbuf + k2*4096 + (o*16 + lq)*32 + quad*8);
                oacc[o] = __builtin_amdgcn_mfma_f32_16x16x32_bf16(pa, bb, oacc[o], 0, 0, 0);
            }
        }
        __builtin_amdgcn_s_setprio(0);

        // drain next-K stage; barrier before buffer swap
        asm volatile("s_waitcnt vmcnt(0)" ::: "memory");
        __builtin_amdgcn_sched_barrier(0);
        __builtin_amdgcn_s_barrier();
        cur ^= 1;

        if (i == pair){
            // epilogue strip A
            #pragma unroll
            for (int r = 0; r < 4; r++){
                float inv = 1.0f / lrun[r];
                int row = qrow + quad*4 + r;
                #pragma unroll
                for (int o = 0; o < 8; o++)
                    dout[(size_t)row * 128 + o*16 + lq] = oacc[o][r] * inv;
            }
            // reset for strip B
            qt = 3 - pair;
            qrow = b*256 + qt*64 + wave*16;
            #pragma unroll
            for (int ks = 0; ks < 4; ks++)
                qf[ks] = *(const short8*)(qws + (size_t)(qrow + lq)*128 + ks*32 + quad*8);
            #pragma unroll
            for (int o2 = 0; o2 < 8; o2++) oacc[o2] = (float4v){0.f,0.f,0.f,0.f};
            #pragma unroll
            for (int r = 0; r < 4; r++){ mrun[r] = MASKV; lrun[r] = 0.f; }
        }
    }
    // epilogue strip B
    #pragma unroll
    for (int r = 0; r < 4; r++){
        float inv = 1.0f / lrun[r];
        int row = qrow + quad*4 + r;
        #pragma unroll
        for (int o = 0; o < 8; o++)
            dout[(size_t)row * 128 + o*16 + lq] = oacc[o][r] * inv;
    }
}

// ============================================================================
// FALLBACK PATH (round-0 verified kernels) — used if workspace too small.
// ============================================================================

__global__ __launch_bounds__(256) void kv_kernel(const float* __restrict__ x,
                                                 const u16* __restrict__ WT,
                                                 float* __restrict__ dout){
    int row0 = blockIdx.x * 64;
    int tid = threadIdx.x;
    int wave = tid >> 6, lane = tid & 63, lq = lane & 15, quad = lane >> 4;

    short8 a[4][4];
    #pragma unroll
    for (int mt = 0; mt < 4; mt++)
        #pragma unroll
        for (int ks = 0; ks < 4; ks++){
            const float* px = x + (size_t)(row0 + mt*16 + lq)*128 + ks*32 + quad*8;
            float4v lo = *(const float4v*)px;
            float4v hi = *(const float4v*)(px + 4);
            short8 s;
            #pragma unroll
            for (int j = 0; j < 4; j++){
                s[j]     = (short)f2bf(lo[j]);
                s[j + 4] = (short)f2bf(hi[j]);
            }
            a[mt][ks] = s;
        }

    #pragma unroll
    for (int nt4 = 0; nt4 < 4; nt4++){
        int gn = wave*64 + nt4*16;
        short8 bfrag[4];
        #pragma unroll
        for (int ks = 0; ks < 4; ks++)
            bfrag[ks] = *(const short8*)(WT + (size_t)(128 + gn + lq)*128 + ks*32 + quad*8);
        float* outp = dout + (size_t)(1 + (gn >> 7)) * BTH;
        int h = (gn & 127) + lq;
        #pragma unroll
        for (int mt = 0; mt < 4; mt++){
            float4v c = {0.f, 0.f, 0.f, 0.f};
            #pragma unroll
            for (int ks = 0; ks < 4; ks++)
                c = __builtin_amdgcn_mfma_f32_16x16x32_bf16(a[mt][ks], bfrag[ks], c, 0, 0, 0);
            int rowb = row0 + mt*16 + quad*4;
            #pragma unroll
            for (int r = 0; r < 4; r++)
                outp[(size_t)(rowb + r) * 128 + h] = c[r];
        }
    }
}

__global__ __launch_bounds__(256) void attn_kernel(const float* __restrict__ x,
                                                   const u16* __restrict__ WT,
                                                   float* __restrict__ dout){
    const float* kg = dout + (size_t)BTH;
    const float* vg = dout + (size_t)2 * BTH;

    __shared__ u16 ksm[64 * 136];
    __shared__ u16 qsm[64 * 136];
    __shared__ u16 vts[128 * 72];
    __shared__ u16 psf[4 * 16 * 72];

    int blk = blockIdx.x;
    int b = blk >> 2, qt = blk & 3;
    int tid = threadIdx.x;
    int wave = tid >> 6, lane = tid & 63, lq = lane & 15, quad = lane >> 4;
    int qrow0 = b * 256 + qt * 64;

    #pragma unroll
    for (int g = 0; g < 8; g++){
        int c2 = g*256 + tid;
        int r = c2 >> 5, f4 = c2 & 31;
        float4v xx = *(const float4v*)(x + (size_t)(qrow0 + r)*128 + f4*4);
        store4bf(ksm + r*136 + f4*4, xx);
    }
    __syncthreads();
    {
        short8 ax[4];
        #pragma unroll
        for (int ks = 0; ks < 4; ks++)
            ax[ks] = *(const short8*)(ksm + (wave*16 + lq)*136 + ks*32 + quad*8);
        #pragma unroll
        for (int nt8 = 0; nt8 < 8; nt8++){
            short8 bq[4];
            #pragma unroll
            for (int ks = 0; ks < 4; ks++)
                bq[ks] = *(const short8*)(WT + (size_t)(nt8*16 + lq)*128 + ks*32 + quad*8);
            float4v c = {0.f, 0.f, 0.f, 0.f};
            #pragma unroll
            for (int ks = 0; ks < 4; ks++)
                c = __builtin_amdgcn_mfma_f32_16x16x32_bf16(ax[ks], bq[ks], c, 0, 0, 0);
            #pragma unroll
            for (int r = 0; r < 4; r++)
                qsm[(wave*16 + quad*4 + r)*136 + nt8*16 + lq] = f2bf(c[r]);
        }
    }
    __syncthreads();
    short8 qf[4];
    #pragma unroll
    for (int ks = 0; ks < 4; ks++)
        qf[ks] = *(const short8*)(qsm + (wave*16 + lq)*136 + ks*32 + quad*8);

    float4v oacc[8];
    #pragma unroll
    for (int i = 0; i < 8; i++) oacc[i] = (float4v){0.f, 0.f, 0.f, 0.f};
    float mrun[4] = {MASKV, MASKV, MASKV, MASKV};
    float lrun[4] = {0.f, 0.f, 0.f, 0.f};

    for (int kt = 0; kt <= qt; kt++){
        int krow0 = b * 256 + kt * 64;
        __syncthreads();
        #pragma unroll
        for (int g = 0; g < 8; g++){
            int c2 = g*256 + tid;
            int r = c2 >> 5, f4 = c2 & 31;
            float4v kk = *(const float4v*)(kg + (size_t)(krow0 + r)*128 + f4*4);
            store4bf(ksm + r*136 + f4*4, kk);
        }
        #pragma unroll
        for (int g = 0; g < 8; g++){
            int c2 = g*256 + tid;
            int key = c2 >> 5, f4 = c2 & 31;
            float4v vv = *(const float4v*)(vg + (size_t)(krow0 + key)*128 + f4*4);
            #pragma unroll
            for (int j = 0; j < 4; j++)
                vts[(f4*4 + j)*72 + key] = f2bf(vv[j]);
        }
        __syncthreads();

        float4v s4[4];
        #pragma unroll
        for (int nt = 0; nt < 4; nt++){
            float4v c = {0.f, 0.f, 0.f, 0.f};
            #pragma unroll
            for (int ks = 0; ks < 4; ks++){
                short8 bb = *(const short8*)(ksm + (nt*16 + lq)*136 + ks*32 + quad*8);
                c = __builtin_amdgcn_mfma_f32_16x16x32_bf16(qf[ks], bb, c, 0, 0, 0);
            }
            #pragma unroll
            for (int r = 0; r < 4; r++)
                c[r] = fminf(fmaxf(c[r], MASKV), 30000.0f);
            s4[nt] = c;
        }
        if (kt == qt){
            #pragma unroll
            for (int nt = 0; nt < 4; nt++)
                #pragma unroll
                for (int r = 0; r < 4; r++){
                    int ci = nt*16 + lq;
                    int ri = wave*16 + quad*4 + r;
                    if (ci > ri) s4[nt][r] = MASKV;
                }
        }
        float p[4][4];
        #pragma unroll
        for (int r = 0; r < 4; r++){
            float mx = fmaxf(fmaxf(s4[0][r], s4[1][r]), fmaxf(s4[2][r], s4[3][r]));
            mx = fmaxf(mx, __shfl_xor(mx, 1));
            mx = fmaxf(mx, __shfl_xor(mx, 2));
            mx = fmaxf(mx, __shfl_xor(mx, 4));
            mx = fmaxf(mx, __shfl_xor(mx, 8));
            float mnew = fmaxf(mrun[r], mx);
            float alpha = __expf(mrun[r] - mnew);
            float rs = 0.f;
            #pragma unroll
            for (int nt = 0; nt < 4; nt++){
                float pv = __expf(s4[nt][r] - mnew);
                p[nt][r] = pv;
                rs += pv;
            }
            rs += __shfl_xor(rs, 1);
            rs += __shfl_xor(rs, 2);
            rs += __shfl_xor(rs, 4);
            rs += __shfl_xor(rs, 8);
            lrun[r] = lrun[r] * alpha + rs;
            mrun[r] = mnew;
            #pragma unroll
            for (int o = 0; o < 8; o++) oacc[o][r] *= alpha;
        }
        #pragma unroll
        for (int nt = 0; nt < 4; nt++)
            #pragma unroll
            for (int r = 0; r < 4; r++)
                psf[wave*1152 + (quad*4 + r)*72 + nt*16 + lq] = f2bf(p[nt][r]);
        __syncthreads();
        #pragma unroll
        for (int k2 = 0; k2 < 2; k2++){
            short8 pa = *(const short8*)(psf + wave*1152 + lq*72 + k2*32 + quad*8);
            #pragma unroll
            for (int o = 0; o < 8; o++){
                short8 bb = *(const short8*)(vts + (o*16 + lq)*72 + k2*32 + quad*8);
                oacc[o] = __builtin_amdgcn_mfma_f32_16x16x32_bf16(pa, bb, oacc[o], 0, 0, 0);
            }
        }
    }
    #pragma unroll
    for (int r = 0; r < 4; r++){
        float inv = 1.0f / lrun[r];
        int row = qrow0 + wave*16 + quad*4 + r;
        #pragma unroll
        for (int o = 0; o < 8; o++)
            dout[(size_t)row * 128 + o*16 + lq] = oacc[o][r] * inv;
    }
}

extern "C" void kernel_launch(void* const* d_in, const int* in_sizes, int n_in,
                              void* d_out, int out_size, void* d_ws, size_t ws_size,
                              hipStream_t stream){
    const float* x  = (const float*)d_in[0];
    const float* Wk = (const float*)d_in[1];
    const float* Wq = (const float*)d_in[2];
    const float* Wv = (const float*)d_in[3];
    float* out = (float*)d_out;
    u16* WT = (u16*)d_ws;                         // 96 KB

    const size_t QOFF = 98304;                    // WT bytes
    const size_t TEN  = (size_t)BTH * 2;          // one bf16 tensor = 32 MiB
    const size_t NEED = QOFF + 3 * TEN;           // ~96.1 MiB

    wt_kernel<<<192, 256, 0, stream>>>(Wq, Wk, Wv, WT);

    if (ws_size >= NEED){
        u16* qws = (u16*)((char*)d_ws + QOFF);
        u16* kws = qws + (size_t)BTH;
        u16* vws = kws + (size_t)BTH;
        proj_kernel <<<2048, 256, 0, stream>>>(x, WT, out, qws, kws, vws);
        attn4_kernel<<<1024, 256, 0, stream>>>(qws, kws, vws, out);
    } else {
        kv_kernel  <<<2048, 256, 0, stream>>>(x, WT, out);
        attn_kernel<<<2048, 256, 0, stream>>>(x, WT, out);
    }
}